// Round 4
// baseline (339.085 us; speedup 1.0000x reference)
//
#include <hip/hip_runtime.h>

// Tricubic B-spline evaluation, p=3, n_ctrl=32 per dim, open-uniform knots.
// queries: [Q,3] f32 in [0,1); control_points: [32^3, 3] f32; out: [Q,3] f32.
//
// Round 3: deep-MLP variant. Spans computed first, all 16 row-gathers issued
// as nontemporal loads into a register array, basis weights computed under
// the load latency, FMAs last. Tests latency-bound vs TCP-rate-bound.

#define P 3
#define NCTRL 32
#define NSEG 29  // n_ctrl - p segments in [0,1]; also #valid ix0 values

typedef float f32x4 __attribute__((ext_vector_type(4)));

// Division-free weights given U (= u*29) and clamped floor ft. Cox-de Boor is
// scale-invariant, so working in knot units matches the reference.
__device__ __forceinline__ void basis_w(float U, float ft, float N[4]) {
    float x  = U - ft;          // left[1]
    float r1 = 1.0f - x;        // right[1]
    float km1 = fmaxf(ft - 1.0f, 0.0f);           // K(t-1)
    float km2 = fmaxf(ft - 2.0f, 0.0f);           // K(t-2)
    float kp2 = fminf(ft + 2.0f, (float)NSEG);    // K(t+2)
    float kp3 = fminf(ft + 3.0f, (float)NSEG);    // K(t+3)
    float l2 = U - km1, l3 = U - km2;
    float r2 = kp2 - U, r3 = kp3 - U;
    float N0 = r1, N1 = x;
    float rcp20 = __builtin_amdgcn_rcpf(ft + 1.0f - km1);
    float rcp21 = __builtin_amdgcn_rcpf(kp2 - ft);
    float temp  = N0 * rcp20;
    N0 = r1 * temp;
    float saved = l2 * temp;
    temp = N1 * rcp21;
    N1 = saved + r2 * temp;
    float N2 = x * temp;
    float rcp30 = __builtin_amdgcn_rcpf(ft + 1.0f - km2);
    float rcp31 = __builtin_amdgcn_rcpf(kp2 - km1);
    float rcp32 = __builtin_amdgcn_rcpf(kp3 - ft);
    temp = N0 * rcp30;
    N0 = r1 * temp;
    saved = l3 * temp;
    temp = N1 * rcp31;
    N1 = saved + r2 * temp;
    saved = l2 * temp;
    temp = N2 * rcp32;
    N2 = saved + r3 * temp;
    N[0] = N0; N[1] = N1; N[2] = N2; N[3] = x * temp;
}

// Repack: rows[((z*32+y)*29 + s)*4 + c] = cp[(z*32+y)*32 + s + c] as float4.
// Each row (4 float4 = 64B) is 64B-aligned -> one cache line per row read.
__global__ void __launch_bounds__(256) repack_rows(const float* __restrict__ cp,
                                                   float4* __restrict__ rows,
                                                   int nelem) {
    int i = blockIdx.x * blockDim.x + threadIdx.x;
    if (i >= nelem) return;
    int row = i >> 2, c = i & 3;
    int z   = row / (NCTRL * NSEG);
    int rem = row % (NCTRL * NSEG);
    int y   = rem / NSEG;
    int s   = rem % NSEG;
    int x   = s + c;
    int src = (z * NCTRL + y) * NCTRL + x;
    rows[i] = make_float4(cp[3 * src + 0], cp[3 * src + 1], cp[3 * src + 2], 0.0f);
}

// 4 lanes per query: lane c handles x-offset c of every row; quad shuffle-reduce.
__global__ void __launch_bounds__(256) spline_eval_quad(const float* __restrict__ q,
                                                        const f32x4* __restrict__ rows,
                                                        float* __restrict__ out, int Q) {
    int t = blockIdx.x * blockDim.x + threadIdx.x;
    int g = t >> 2;
    int c = t & 3;
    if (g >= Q) return;
    float ux = q[3 * g + 0];
    float uy = q[3 * g + 1];
    float uz = q[3 * g + 2];

    // spans only (cheap) -> addresses ready ASAP
    float Ux = ux * (float)NSEG, Uy = uy * (float)NSEG, Uz = uz * (float)NSEG;
    float ftx = fminf(fmaxf(floorf(Ux), 0.0f), (float)(NSEG - 1));
    float fty = fminf(fmaxf(floorf(Uy), 0.0f), (float)(NSEG - 1));
    float ftz = fminf(fmaxf(floorf(Uz), 0.0f), (float)(NSEG - 1));
    int ix0 = (int)ftx, iy0 = (int)fty, iz0 = (int)ftz;

    const int base = ((iz0 * NCTRL) + iy0) * NSEG + ix0;
    const f32x4* rp = rows + (size_t)base * 4 + c;

    // issue all 16 row gathers (nontemporal: no L1 reuse exists)
    f32x4 cv[16];
#pragma unroll
    for (int k = 0; k < 4; ++k)
#pragma unroll
        for (int j = 0; j < 4; ++j)
            cv[k * 4 + j] = __builtin_nontemporal_load(&rp[(k * NCTRL + j) * NSEG * 4]);

    // basis weights computed under the load latency
    float Bx[4], By[4], Bz[4];
    basis_w(Ux, ftx, Bx);
    basis_w(Uy, fty, By);
    basis_w(Uz, ftz, Bz);
    float wzy[16];
#pragma unroll
    for (int k = 0; k < 4; ++k)
#pragma unroll
        for (int j = 0; j < 4; ++j)
            wzy[k * 4 + j] = Bz[k] * By[j];

    float ax = 0.f, ay = 0.f, az = 0.f;
#pragma unroll
    for (int r = 0; r < 16; ++r) {
        float w = wzy[r];
        ax = fmaf(w, cv[r].x, ax);
        ay = fmaf(w, cv[r].y, ay);
        az = fmaf(w, cv[r].z, az);
    }
    // fold this lane's Bx once, then quad-reduce
    float bxc = Bx[c];
    ax *= bxc; ay *= bxc; az *= bxc;
    ax += __shfl_xor(ax, 1); ax += __shfl_xor(ax, 2);
    ay += __shfl_xor(ay, 1); ay += __shfl_xor(ay, 2);
    az += __shfl_xor(az, 1); az += __shfl_xor(az, 2);
    float val = (c == 0) ? ax : (c == 1) ? ay : az;
    if (c < 3) out[3 * g + c] = val;
}

// Fallback if workspace is too small: direct [n,3]-layout gather per thread.
__global__ void __launch_bounds__(256) spline_eval_direct(const float* __restrict__ q,
                                                          const float* __restrict__ cp,
                                                          float* __restrict__ out, int Q) {
    int idx = blockIdx.x * blockDim.x + threadIdx.x;
    if (idx >= Q) return;
    float U[3], ft[3];
    int s[3];
#pragma unroll
    for (int d = 0; d < 3; ++d) {
        U[d]  = q[3 * idx + d] * (float)NSEG;
        ft[d] = fminf(fmaxf(floorf(U[d]), 0.0f), (float)(NSEG - 1));
        s[d]  = (int)ft[d];
    }
    float Bx[4], By[4], Bz[4];
    basis_w(U[0], ft[0], Bx);
    basis_w(U[1], ft[1], By);
    basis_w(U[2], ft[2], Bz);
    float ax = 0.f, ay = 0.f, az = 0.f;
#pragma unroll
    for (int k = 0; k < 4; ++k) {
#pragma unroll
        for (int j = 0; j < 4; ++j) {
            float w = Bz[k] * By[j];
            int base = ((s[2] + k) * NCTRL + (s[1] + j)) * NCTRL + s[0];
#pragma unroll
            for (int i = 0; i < 4; ++i) {
                float wi = w * Bx[i];
                ax = fmaf(wi, cp[3 * (base + i) + 0], ax);
                ay = fmaf(wi, cp[3 * (base + i) + 1], ay);
                az = fmaf(wi, cp[3 * (base + i) + 2], az);
            }
        }
    }
    out[3 * idx + 0] = ax;
    out[3 * idx + 1] = ay;
    out[3 * idx + 2] = az;
}

extern "C" void kernel_launch(void* const* d_in, const int* in_sizes, int n_in,
                              void* d_out, int out_size, void* d_ws, size_t ws_size,
                              hipStream_t stream) {
    const float* q  = (const float*)d_in[0];
    const float* cp = (const float*)d_in[1];
    float* out = (float*)d_out;
    int Q = in_sizes[0] / 3;

    const int nrows = NCTRL * NCTRL * NSEG;   // 29696
    const int nelem = nrows * 4;              // 118784 float4 = 1.86 MB
    if (ws_size >= (size_t)nelem * sizeof(float4)) {
        float4* rows = (float4*)d_ws;
        repack_rows<<<(nelem + 255) / 256, 256, 0, stream>>>(cp, rows, nelem);
        long long nthreads = 4LL * Q;
        spline_eval_quad<<<(int)((nthreads + 255) / 256), 256, 0, stream>>>(
            q, (const f32x4*)rows, out, Q);
    } else {
        spline_eval_direct<<<(Q + 255) / 256, 256, 0, stream>>>(q, cp, out, Q);
    }
}

// Round 5
// 200.069 us; speedup vs baseline: 1.6948x; 1.6948x over previous
//
#include <hip/hip_runtime.h>

// Tricubic B-spline evaluation, p=3, n_ctrl=32 per dim, open-uniform knots.
// queries: [Q,3] f32 in [0,1); control_points: [32^3, 3] f32; out: [Q,3] f32.
//
// Round 4: revert nontemporal (round-4 lesson: gathers are L2-resident; nt
// bypassed L2 -> 354 MB HBM fetch). Force true 16-deep load batching with
// sched_barrier(0) so all 16 row gathers are in flight before the FMA chain
// (round-3/4 lesson: compiler sinks loads to keep VGPR=32, killing MLP).

#define P 3
#define NCTRL 32
#define NSEG 29  // n_ctrl - p segments in [0,1]; also #valid ix0 values

typedef float f32x4 __attribute__((ext_vector_type(4)));

// Division-free weights given U (= u*29) and clamped floor ft. Cox-de Boor is
// scale-invariant, so working in knot units matches the reference.
__device__ __forceinline__ void basis_w(float U, float ft, float N[4]) {
    float x  = U - ft;          // left[1]
    float r1 = 1.0f - x;        // right[1]
    float km1 = fmaxf(ft - 1.0f, 0.0f);           // K(t-1)
    float km2 = fmaxf(ft - 2.0f, 0.0f);           // K(t-2)
    float kp2 = fminf(ft + 2.0f, (float)NSEG);    // K(t+2)
    float kp3 = fminf(ft + 3.0f, (float)NSEG);    // K(t+3)
    float l2 = U - km1, l3 = U - km2;
    float r2 = kp2 - U, r3 = kp3 - U;
    float N0 = r1, N1 = x;
    float rcp20 = __builtin_amdgcn_rcpf(ft + 1.0f - km1);
    float rcp21 = __builtin_amdgcn_rcpf(kp2 - ft);
    float temp  = N0 * rcp20;
    N0 = r1 * temp;
    float saved = l2 * temp;
    temp = N1 * rcp21;
    N1 = saved + r2 * temp;
    float N2 = x * temp;
    float rcp30 = __builtin_amdgcn_rcpf(ft + 1.0f - km2);
    float rcp31 = __builtin_amdgcn_rcpf(kp2 - km1);
    float rcp32 = __builtin_amdgcn_rcpf(kp3 - ft);
    temp = N0 * rcp30;
    N0 = r1 * temp;
    saved = l3 * temp;
    temp = N1 * rcp31;
    N1 = saved + r2 * temp;
    saved = l2 * temp;
    temp = N2 * rcp32;
    N2 = saved + r3 * temp;
    N[0] = N0; N[1] = N1; N[2] = N2; N[3] = x * temp;
}

// Repack: rows[((z*32+y)*29 + s)*4 + c] = cp[(z*32+y)*32 + s + c] as float4.
// Each row (4 float4 = 64B) is 64B-aligned -> one cache line per row read.
__global__ void __launch_bounds__(256) repack_rows(const float* __restrict__ cp,
                                                   float4* __restrict__ rows,
                                                   int nelem) {
    int i = blockIdx.x * blockDim.x + threadIdx.x;
    if (i >= nelem) return;
    int row = i >> 2, c = i & 3;
    int z   = row / (NCTRL * NSEG);
    int rem = row % (NCTRL * NSEG);
    int y   = rem / NSEG;
    int s   = rem % NSEG;
    int x   = s + c;
    int src = (z * NCTRL + y) * NCTRL + x;
    rows[i] = make_float4(cp[3 * src + 0], cp[3 * src + 1], cp[3 * src + 2], 0.0f);
}

// 4 lanes per query: lane c handles x-offset c of every row; quad shuffle-reduce.
__global__ void __launch_bounds__(256) spline_eval_quad(const float* __restrict__ q,
                                                        const f32x4* __restrict__ rows,
                                                        float* __restrict__ out, int Q) {
    int t = blockIdx.x * blockDim.x + threadIdx.x;
    int g = t >> 2;
    int c = t & 3;
    if (g >= Q) return;
    float ux = q[3 * g + 0];
    float uy = q[3 * g + 1];
    float uz = q[3 * g + 2];

    // spans only (cheap) -> addresses ready ASAP
    float Ux = ux * (float)NSEG, Uy = uy * (float)NSEG, Uz = uz * (float)NSEG;
    float ftx = fminf(fmaxf(floorf(Ux), 0.0f), (float)(NSEG - 1));
    float fty = fminf(fmaxf(floorf(Uy), 0.0f), (float)(NSEG - 1));
    float ftz = fminf(fmaxf(floorf(Uz), 0.0f), (float)(NSEG - 1));
    int ix0 = (int)ftx, iy0 = (int)fty, iz0 = (int)ftz;

    const int base = ((iz0 * NCTRL) + iy0) * NSEG + ix0;
    const f32x4* rp = rows + (size_t)base * 4 + c;

    // issue all 16 row gathers (L2-cached; table is 1.86 MB and L2-resident)
    f32x4 cv[16];
#pragma unroll
    for (int k = 0; k < 4; ++k)
#pragma unroll
        for (int j = 0; j < 4; ++j)
            cv[k * 4 + j] = rp[(k * NCTRL + j) * NSEG * 4];

    // basis weights computed under the load latency (same scheduling region)
    float Bx[4], By[4], Bz[4];
    basis_w(Ux, ftx, Bx);
    basis_w(Uy, fty, By);
    basis_w(Uz, ftz, Bz);
    float wzy[16];
#pragma unroll
    for (int k = 0; k < 4; ++k)
#pragma unroll
        for (int j = 0; j < 4; ++j)
            wzy[k * 4 + j] = Bz[k] * By[j];

    // hard scheduling fence: nothing crosses -> all 16 loads must be issued
    // (and their results allocated) before any consuming FMA below.
    __builtin_amdgcn_sched_barrier(0);

    float ax = 0.f, ay = 0.f, az = 0.f;
#pragma unroll
    for (int r = 0; r < 16; ++r) {
        float w = wzy[r];
        ax = fmaf(w, cv[r].x, ax);
        ay = fmaf(w, cv[r].y, ay);
        az = fmaf(w, cv[r].z, az);
    }
    // fold this lane's Bx once, then quad-reduce
    float bxc = Bx[c];
    ax *= bxc; ay *= bxc; az *= bxc;
    ax += __shfl_xor(ax, 1); ax += __shfl_xor(ax, 2);
    ay += __shfl_xor(ay, 1); ay += __shfl_xor(ay, 2);
    az += __shfl_xor(az, 1); az += __shfl_xor(az, 2);
    float val = (c == 0) ? ax : (c == 1) ? ay : az;
    if (c < 3) out[3 * g + c] = val;
}

// Fallback if workspace is too small: direct [n,3]-layout gather per thread.
__global__ void __launch_bounds__(256) spline_eval_direct(const float* __restrict__ q,
                                                          const float* __restrict__ cp,
                                                          float* __restrict__ out, int Q) {
    int idx = blockIdx.x * blockDim.x + threadIdx.x;
    if (idx >= Q) return;
    float U[3], ft[3];
    int s[3];
#pragma unroll
    for (int d = 0; d < 3; ++d) {
        U[d]  = q[3 * idx + d] * (float)NSEG;
        ft[d] = fminf(fmaxf(floorf(U[d]), 0.0f), (float)(NSEG - 1));
        s[d]  = (int)ft[d];
    }
    float Bx[4], By[4], Bz[4];
    basis_w(U[0], ft[0], Bx);
    basis_w(U[1], ft[1], By);
    basis_w(U[2], ft[2], Bz);
    float ax = 0.f, ay = 0.f, az = 0.f;
#pragma unroll
    for (int k = 0; k < 4; ++k) {
#pragma unroll
        for (int j = 0; j < 4; ++j) {
            float w = Bz[k] * By[j];
            int base = ((s[2] + k) * NCTRL + (s[1] + j)) * NCTRL + s[0];
#pragma unroll
            for (int i = 0; i < 4; ++i) {
                float wi = w * Bx[i];
                ax = fmaf(wi, cp[3 * (base + i) + 0], ax);
                ay = fmaf(wi, cp[3 * (base + i) + 1], ay);
                az = fmaf(wi, cp[3 * (base + i) + 2], az);
            }
        }
    }
    out[3 * idx + 0] = ax;
    out[3 * idx + 1] = ay;
    out[3 * idx + 2] = az;
}

extern "C" void kernel_launch(void* const* d_in, const int* in_sizes, int n_in,
                              void* d_out, int out_size, void* d_ws, size_t ws_size,
                              hipStream_t stream) {
    const float* q  = (const float*)d_in[0];
    const float* cp = (const float*)d_in[1];
    float* out = (float*)d_out;
    int Q = in_sizes[0] / 3;

    const int nrows = NCTRL * NCTRL * NSEG;   // 29696
    const int nelem = nrows * 4;              // 118784 float4 = 1.86 MB
    if (ws_size >= (size_t)nelem * sizeof(float4)) {
        float4* rows = (float4*)d_ws;
        repack_rows<<<(nelem + 255) / 256, 256, 0, stream>>>(cp, rows, nelem);
        long long nthreads = 4LL * Q;
        spline_eval_quad<<<(int)((nthreads + 255) / 256), 256, 0, stream>>>(
            q, (const f32x4*)rows, out, Q);
    } else {
        spline_eval_direct<<<(Q + 255) / 256, 256, 0, stream>>>(q, cp, out, Q);
    }
}